// Round 6
// baseline (768.835 us; speedup 1.0000x reference)
//
#include <hip/hip_runtime.h>
#include <hip/hip_bf16.h>

// MemoryGraph: B=8, NC=256, Nc=128, D_n=64, HS=256, HM=128, ALPHA=2
// R6: re-fused K1 (msg+agg+state) with LDS shrunk to 24.5K -> 6 blocks/CU
//     (24 waves/CU) for TLP latency hiding. mT_s buffer reused as the agg
//     C->A relayout stage after an extra barrier. No W reg-prefetch (TLP
//     covers inline loads). K2 hebb_kernel unchanged (at HBM roofline).

#define NCELL 256

typedef __attribute__((ext_vector_type(8))) short bf16x8;
typedef __attribute__((ext_vector_type(4))) float f32x4;
typedef __attribute__((ext_vector_type(4))) unsigned short u16x4;

#define MFMA(a, b, c) __builtin_amdgcn_mfma_f32_16x16x32_bf16((a), (b), (c), 0, 0, 0)

__device__ __forceinline__ unsigned short f2bf(float f) {
    return __builtin_bit_cast(unsigned short, __float2bfloat16(f));
}
__device__ __forceinline__ float frcp(float x) { return __builtin_amdgcn_rcpf(x); }
__device__ __forceinline__ float sigm(float v) { return frcp(1.0f + __expf(-v)); }
__device__ __forceinline__ float ftanh(float x) {
    float e = __expf(2.0f * x);
    return 1.0f - 2.0f * frcp(e + 1.0f);
}

// Swizzled LDS index helpers (ushort units). 16B-granule XOR swizzle on row.
__device__ __forceinline__ int sw64(int row, int col) {   // [R][64] bf16 tile
    return row * 64 + ((((col >> 3) ^ row) & 7) << 3) + (col & 7);
}
__device__ __forceinline__ int sw128(int row, int col) {  // [R][128] bf16 tile
    return row * 128 + (((col >> 3) ^ (row & 7)) << 3) + (col & 7);
}
__device__ __forceinline__ int sw32(int row, int col) {   // [32][32] bf16 tile
    return row * 32 + ((((col >> 3) ^ row) & 3) << 3) + (col & 7);
}

__global__ void cvt_w(const float* __restrict__ a, const float* __restrict__ b,
                      const float* __restrict__ c, const float* __restrict__ d,
                      unsigned short* __restrict__ dst) {
    int i = blockIdx.x * 256 + threadIdx.x;   // 65536 total
    float v;
    if (i < 8192) v = a[i];                    // msg_w1 [128][64]
    else if (i < 16384) v = b[i - 8192];       // msg_w2 [64][128]
    else if (i < 49152) v = c[i - 16384];      // state_w1 [256][128]
    else v = d[i - 49152];                     // state_w2 [64][256]
    dst[i] = f2bf(v);
}

// ================= K1: fused cell chain =================
__global__ __launch_bounds__(256, 6)
void cell_kernel(const float* __restrict__ x, const float* __restrict__ h,
                 const float* __restrict__ W, const float* __restrict__ decay,
                 const float* __restrict__ nid,
                 const float* __restrict__ sb1, const float* __restrict__ sb2,
                 const float* __restrict__ mb1, const float* __restrict__ mb2,
                 const float* __restrict__ injw, const float* __restrict__ injb,
                 const float* __restrict__ dgl,
                 const unsigned short* __restrict__ wbf,
                 float* __restrict__ out) {
    const int cell = blockIdx.x;              // b*NC + c
    const int c = cell & (NCELL - 1);
    const int tid = threadIdx.x;
    const int wv = tid >> 6;
    const int lane = tid & 63;
    const int lr = lane & 15;
    const int lg = lane >> 4;

    float* out_h = out;
    float* out_m = out + 16777216;
    float* out_d = out + 67108864;

    const unsigned short* w1m = wbf;              // [128][64]
    const unsigned short* w2m = wbf + 8192;       // [64][128]
    const unsigned short* w1s = wbf + 16384;      // [256][128]
    const unsigned short* w2s = wbf + 49152;      // [64][256]

    // LDS: 24.5 KB -> 6 blocks/CU (24 waves/CU)
    __shared__ alignas(16) unsigned short mT_s[8192];     // 16K: m^T [64][128]; post-B3: agg stage [128][64]
    __shared__ alignas(16) unsigned short hbuf_all[4096]; // 8K: per-wave [32][32]
    __shared__ float inj_s[128];                          // 512B
    unsigned short* hbuf = hbuf_all + wv * 1024;
    unsigned short* st_s = mT_s;                          // alias (phase-separated by B3)

    // ---- injection (wave-0 private: only rows 0,1 consume it) ----
    if (wv == 0) {
        const float* xr = x + cell * 64;
        const float* i0 = injw + (c * 128 + lane) * 64;
        const float* i1 = i0 + 64 * 64;
        float acc0 = injb[c * 128 + lane];
        float acc1 = injb[c * 128 + 64 + lane];
        #pragma unroll
        for (int d4 = 0; d4 < 16; ++d4) {
            float4 xv = ((const float4*)xr)[d4];
            float4 a = ((const float4*)i0)[d4];
            float4 b = ((const float4*)i1)[d4];
            acc0 += a.x * xv.x + a.y * xv.y + a.z * xv.z + a.w * xv.w;
            acc1 += b.x * xv.x + b.y * xv.y + b.z * xv.z + b.w * xv.w;
        }
        inj_s[lane] = acc0;
        inj_s[64 + lane] = acc1;
    }
    // no barrier: inj_s produced and consumed by wave 0 only

    // ---- A-frags of h_id straight from global ----
    bf16x8 aH[2][2];
    #pragma unroll
    for (int rt = 0; rt < 2; ++rt)
        #pragma unroll
        for (int ks = 0; ks < 2; ++ks) {
            const int row = wv * 32 + rt * 16 + lr;
            const int col = ks * 32 + lg * 8;
            const float* hr = h + (size_t)(cell * 128 + row) * 64 + col;
            const float* nr = nid + (size_t)(c * 128 + row) * 64 + col;
            float4 a0 = *(const float4*)hr;
            float4 a1 = *(const float4*)(hr + 4);
            float4 n0 = *(const float4*)nr;
            float4 n1 = *(const float4*)(nr + 4);
            float v[8] = {a0.x, a0.y, a0.z, a0.w, a1.x, a1.y, a1.z, a1.w};
            float nn[8] = {n0.x, n0.y, n0.z, n0.w, n1.x, n1.y, n1.z, n1.w};
            unsigned short us[8];
            #pragma unroll
            for (int j = 0; j < 8; ++j) {
                float hv = v[j] + nn[j];
                if (row < 2) hv += inj_s[row * 64 + col + j];
                us[j] = f2bf(hv);
            }
            aH[rt][ks] = *(bf16x8*)us;
        }

    // ---- msg MLP ----
    f32x4 accM[2][4];
    #pragma unroll
    for (int rt = 0; rt < 2; ++rt)
        #pragma unroll
        for (int dt = 0; dt < 4; ++dt)
            accM[rt][dt] = (f32x4){0.f, 0.f, 0.f, 0.f};

    #pragma unroll 2
    for (int ch = 0; ch < 4; ++ch) {
        f32x4 accH[2][2];
        #pragma unroll
        for (int rt = 0; rt < 2; ++rt)
            #pragma unroll
            for (int ht = 0; ht < 2; ++ht)
                accH[rt][ht] = (f32x4){0.f, 0.f, 0.f, 0.f};
        #pragma unroll
        for (int ks = 0; ks < 2; ++ks)
            #pragma unroll
            for (int ht = 0; ht < 2; ++ht) {
                bf16x8 bw = *(const bf16x8*)&w1m[(ch * 32 + ht * 16 + lr) * 64 + ks * 32 + lg * 8];
                #pragma unroll
                for (int rt = 0; rt < 2; ++rt)
                    accH[rt][ht] = MFMA(aH[rt][ks], bw, accH[rt][ht]);
            }
        #pragma unroll
        for (int rt = 0; rt < 2; ++rt)
            #pragma unroll
            for (int ht = 0; ht < 2; ++ht) {
                float b1v = mb1[ch * 32 + ht * 16 + lr];
                #pragma unroll
                for (int r = 0; r < 4; ++r) {
                    float t = ftanh(accH[rt][ht][r] + b1v);
                    hbuf[sw32(rt * 16 + lg * 4 + r, ht * 16 + lr)] = f2bf(t);
                }
            }
        #pragma unroll
        for (int rt = 0; rt < 2; ++rt) {
            bf16x8 aM = *(const bf16x8*)&hbuf[sw32(rt * 16 + lr, lg * 8)];
            #pragma unroll
            for (int dt = 0; dt < 4; ++dt) {
                bf16x8 bw = *(const bf16x8*)&w2m[(dt * 16 + lr) * 128 + ch * 32 + lg * 8];
                accM[rt][dt] = MFMA(aM, bw, accM[rt][dt]);
            }
        }
    }
    // epilogue: +b2, write m to global (f32) + mT_s (bf16)
    #pragma unroll
    for (int rt = 0; rt < 2; ++rt)
        #pragma unroll
        for (int dt = 0; dt < 4; ++dt) {
            float b2v = mb2[dt * 16 + lr];
            #pragma unroll
            for (int r = 0; r < 4; ++r) {
                float mv = accM[rt][dt][r] + b2v;
                int n = wv * 32 + rt * 16 + lg * 4 + r;
                int dcol = dt * 16 + lr;
                out_m[(size_t)(cell * 128 + n) * 64 + dcol] = mv;
                mT_s[sw128(dcol, n)] = f2bf(mv);
            }
        }
    __syncthreads();   // B2: mT_s ready

    // ---- agg = W @ m (inline W f32 loads; TLP hides latency) ----
    f32x4 accA[2][4];
    #pragma unroll
    for (int rt = 0; rt < 2; ++rt)
        #pragma unroll
        for (int dt = 0; dt < 4; ++dt)
            accA[rt][dt] = (f32x4){0.f, 0.f, 0.f, 0.f};
    {
        const float* Wbase = W + (size_t)cell * 16384;
        #pragma unroll
        for (int ks = 0; ks < 4; ++ks)
            #pragma unroll
            for (int rt = 0; rt < 2; ++rt) {
                const float* wr = Wbase + (wv * 32 + rt * 16 + lr) * 128 + ks * 32 + lg * 8;
                float4 wa = *(const float4*)wr;
                float4 wb = *(const float4*)(wr + 4);
                unsigned short uw[8] = {f2bf(wa.x), f2bf(wa.y), f2bf(wa.z), f2bf(wa.w),
                                        f2bf(wb.x), f2bf(wb.y), f2bf(wb.z), f2bf(wb.w)};
                bf16x8 aW = *(bf16x8*)uw;
                #pragma unroll
                for (int dt = 0; dt < 4; ++dt) {
                    bf16x8 bm = *(const bf16x8*)&mT_s[sw128(dt * 16 + lr, ks * 32 + lg * 8)];
                    accA[rt][dt] = MFMA(aW, bm, accA[rt][dt]);
                }
            }
    }
    __syncthreads();   // B3: all waves done reading mT_s; safe to overwrite as stage

    // C-layout -> A-layout via stage (own-wave rows; no further barrier)
    #pragma unroll
    for (int rt = 0; rt < 2; ++rt)
        #pragma unroll
        for (int dt = 0; dt < 4; ++dt)
            #pragma unroll
            for (int r = 0; r < 4; ++r)
                st_s[sw64(wv * 32 + rt * 16 + lg * 4 + r, dt * 16 + lr)] = f2bf(accA[rt][dt][r]);

    bf16x8 aG[2][2];
    #pragma unroll
    for (int rt = 0; rt < 2; ++rt)
        #pragma unroll
        for (int ks = 0; ks < 2; ++ks)
            aG[rt][ks] = *(const bf16x8*)&st_s[sw64(wv * 32 + rt * 16 + lr, ks * 32 + lg * 8)];

    // ---- state MLP ----
    f32x4 accD[2][4];
    #pragma unroll
    for (int rt = 0; rt < 2; ++rt)
        #pragma unroll
        for (int dt = 0; dt < 4; ++dt)
            accD[rt][dt] = (f32x4){0.f, 0.f, 0.f, 0.f};

    #pragma unroll 2
    for (int ch = 0; ch < 8; ++ch) {
        f32x4 accS[2][2];
        #pragma unroll
        for (int rt = 0; rt < 2; ++rt)
            #pragma unroll
            for (int ht = 0; ht < 2; ++ht)
                accS[rt][ht] = (f32x4){0.f, 0.f, 0.f, 0.f};
        #pragma unroll
        for (int ks = 0; ks < 4; ++ks)
            #pragma unroll
            for (int ht = 0; ht < 2; ++ht) {
                bf16x8 bw = *(const bf16x8*)&w1s[(ch * 32 + ht * 16 + lr) * 128 + ks * 32 + lg * 8];
                #pragma unroll
                for (int rt = 0; rt < 2; ++rt) {
                    bf16x8 af = (ks < 2) ? aH[rt][ks] : aG[rt][ks - 2];
                    accS[rt][ht] = MFMA(af, bw, accS[rt][ht]);
                }
            }
        #pragma unroll
        for (int rt = 0; rt < 2; ++rt)
            #pragma unroll
            for (int ht = 0; ht < 2; ++ht) {
                float bv = sb1[ch * 32 + ht * 16 + lr];
                #pragma unroll
                for (int r = 0; r < 4; ++r) {
                    float t = ftanh(accS[rt][ht][r] + bv);
                    hbuf[sw32(rt * 16 + lg * 4 + r, ht * 16 + lr)] = f2bf(t);
                }
            }
        #pragma unroll
        for (int rt = 0; rt < 2; ++rt) {
            bf16x8 aS = *(const bf16x8*)&hbuf[sw32(rt * 16 + lr, lg * 8)];
            #pragma unroll
            for (int dt = 0; dt < 4; ++dt) {
                bf16x8 bw = *(const bf16x8*)&w2s[(dt * 16 + lr) * 256 + ch * 32 + lg * 8];
                accD[rt][dt] = MFMA(aS, bw, accD[rt][dt]);
            }
        }
    }

    // ---- decay_new, h_new ----
    float dnew_r[2][4];
    #pragma unroll
    for (int rt = 0; rt < 2; ++rt)
        #pragma unroll
        for (int r = 0; r < 4; ++r) {
            float s = 0.f;
            #pragma unroll
            for (int dt = 0; dt < 4; ++dt) {
                accD[rt][dt][r] += sb2[dt * 16 + lr];
                s += accD[rt][dt][r];
            }
            s += __shfl_xor(s, 1);
            s += __shfl_xor(s, 2);
            s += __shfl_xor(s, 4);
            s += __shfl_xor(s, 8);
            int row = wv * 32 + rt * 16 + lg * 4 + r;
            float mean = s * (1.0f / 64.0f);
            float dg = 0.5f * sigm(dgl[c * 128 + row]);
            float dn = (1.0f - dg) * decay[cell * 128 + row] + dg * sigm(mean);
            if (lr == 0) out_d[cell * 128 + row] = dn;
            dnew_r[rt][r] = dn;
        }
    #pragma unroll
    for (int rt = 0; rt < 2; ++rt)
        #pragma unroll
        for (int r = 0; r < 4; ++r) {
            int row = wv * 32 + rt * 16 + lg * 4 + r;
            float dn = dnew_r[rt][r];
            const float* hr = h + (size_t)(cell * 128 + row) * 64;
            #pragma unroll
            for (int dt = 0; dt < 4; ++dt) {
                int col = dt * 16 + lr;
                float hpost = hr[col];
                if (row < 2) hpost += inj_s[row * 64 + col];
                float hn = (1.0f - dn) * hpost + dn * ftanh(accD[rt][dt][r]);
                out_h[(size_t)(cell * 128 + row) * 64 + col] = hn;
            }
        }
}

// ================= K2: outer + hebbian/W streaming update =================
__global__ __launch_bounds__(256, 4)
void hebb_kernel(const float* __restrict__ W, const float* __restrict__ hebb,
                 const float* __restrict__ wdl, const float* __restrict__ hdl,
                 float* __restrict__ out) {
    const int cell = blockIdx.x;
    const int c = cell & (NCELL - 1);
    const int tid = threadIdx.x;
    const int wv = tid >> 6;
    const int lane = tid & 63;
    const int lr = lane & 15;
    const int lg = lane >> 4;

    const float* hsrc = out + (size_t)cell * 8192;              // h_new
    const float* msrc = out + 16777216 + (size_t)cell * 8192;   // m
    float* out_W  = out + 33554432;
    float* out_hb = out + 67371008;

    __shared__ alignas(16) unsigned char smem[32768];
    unsigned short* hA = (unsigned short*)smem;            // [128][64] h_new bf16
    unsigned short* mB = (unsigned short*)(smem + 16384);  // [128][64] m bf16

    // ---- stage h_new, m -> LDS bf16 (coalesced float4) ----
    #pragma unroll
    for (int g = 0; g < 8; ++g) {
        int idx = g * 1024 + tid * 4;
        int row = idx >> 6, col = idx & 63;
        float4 hv = *(const float4*)(hsrc + idx);
        float4 mv = *(const float4*)(msrc + idx);
        u16x4 hu = {f2bf(hv.x), f2bf(hv.y), f2bf(hv.z), f2bf(hv.w)};
        u16x4 mu = {f2bf(mv.x), f2bf(mv.y), f2bf(mv.z), f2bf(mv.w)};
        *(u16x4*)&hA[sw64(row, col)] = hu;
        *(u16x4*)&mB[sw64(row, col)] = mu;
    }
    __syncthreads();

    // ---- outer = h_new @ m^T ----
    bf16x8 aO[2][2];
    #pragma unroll
    for (int rt = 0; rt < 2; ++rt)
        #pragma unroll
        for (int ks = 0; ks < 2; ++ks)
            aO[rt][ks] = *(const bf16x8*)&hA[sw64(wv * 32 + rt * 16 + lr, ks * 32 + lg * 8)];

    f32x4 accO[2][8];
    #pragma unroll
    for (int rt = 0; rt < 2; ++rt)
        #pragma unroll
        for (int jt = 0; jt < 8; ++jt)
            accO[rt][jt] = (f32x4){0.f, 0.f, 0.f, 0.f};
    #pragma unroll
    for (int jt = 0; jt < 8; ++jt)
        #pragma unroll
        for (int ks = 0; ks < 2; ++ks) {
            bf16x8 bm = *(const bf16x8*)&mB[sw64(jt * 16 + lr, ks * 32 + lg * 8)];
            #pragma unroll
            for (int rt = 0; rt < 2; ++rt)
                accO[rt][jt] = MFMA(aO[rt][ks], bm, accO[rt][jt]);
        }

    // ---- hebbian / W update + rms-norm ----
    #pragma unroll
    for (int rt = 0; rt < 2; ++rt)
        #pragma unroll
        for (int r = 0; r < 4; ++r) {
            int i = wv * 32 + rt * 16 + lg * 4 + r;
            float hg = 0.5f * sigm(hdl[c * 128 + i]);
            float wg = 0.5f * sigm(wdl[c * 128 + i]);
            const float* hbr = hebb + (size_t)(cell * 128 + i) * 128;
            const float* Wr = W + (size_t)(cell * 128 + i) * 128;
            float* ohb = out_hb + (size_t)(cell * 128 + i) * 128;
            float wpre[8];
            float ss = 0.f;
            #pragma unroll
            for (int jt = 0; jt < 8; ++jt) {
                int j = jt * 16 + lr;
                float o = accO[rt][jt][r] * (1.0f / 64.0f);
                float hbn = (1.0f - hg) * hbr[j] + hg * o;
                ohb[j] = hbn;
                float wp = (1.0f - wg) * Wr[j] + wg * hbn;
                wpre[jt] = wp;
                ss += wp * wp;
            }
            ss += __shfl_xor(ss, 1);
            ss += __shfl_xor(ss, 2);
            ss += __shfl_xor(ss, 4);
            ss += __shfl_xor(ss, 8);
            float scale = rsqrtf(ss * (1.0f / 128.0f) + 1e-6f);
            float* oW = out_W + (size_t)(cell * 128 + i) * 128;
            #pragma unroll
            for (int jt = 0; jt < 8; ++jt)
                oW[jt * 16 + lr] = wpre[jt] * scale;
        }
}

extern "C" void kernel_launch(void* const* d_in, const int* in_sizes, int n_in,
                              void* d_out, int out_size, void* d_ws, size_t ws_size,
                              hipStream_t stream) {
    const float* x    = (const float*)d_in[0];
    const float* h    = (const float*)d_in[1];
    const float* W    = (const float*)d_in[2];
    const float* dec  = (const float*)d_in[3];
    const float* hebb = (const float*)d_in[4];
    const float* nid  = (const float*)d_in[5];
    const float* sw1  = (const float*)d_in[6];
    const float* sb1  = (const float*)d_in[7];
    const float* sw2  = (const float*)d_in[8];
    const float* sb2  = (const float*)d_in[9];
    const float* mw1  = (const float*)d_in[10];
    const float* mb1  = (const float*)d_in[11];
    const float* mw2  = (const float*)d_in[12];
    const float* mb2  = (const float*)d_in[13];
    const float* injw = (const float*)d_in[14];
    const float* injb = (const float*)d_in[15];
    const float* wdl  = (const float*)d_in[16];
    const float* dgl  = (const float*)d_in[17];
    const float* hdl  = (const float*)d_in[18];

    unsigned short* wbf = (unsigned short*)d_ws;   // 65536 bf16 = 128 KB

    cvt_w<<<256, 256, 0, stream>>>(mw1, mw2, sw1, sw2, wbf);
    cell_kernel<<<2048, 256, 0, stream>>>(x, h, W, dec, nid, sb1, sb2, mb1, mb2,
                                          injw, injb, dgl, wbf, (float*)d_out);
    hebb_kernel<<<2048, 256, 0, stream>>>(W, hebb, wdl, hdl, (float*)d_out);
}

// Round 8
// 391.342 us; speedup vs baseline: 1.9646x; 1.9646x over previous
//
#include <hip/hip_runtime.h>
#include <hip/hip_bf16.h>

// MemoryGraph: B=8, NC=256, Nc=128, D_n=64, HS=256, HM=128, ALPHA=2
// R8 = R7 resubmitted (container died; no data). Persistent-block design.
//   cell_kernel: grid 512 x 512 threads (2 blocks/CU). Block = (c, half);
//   loops 4 cells (b). Weights pre-swizzled by cvt_w into d_ws "LDS images";
//   w2m+w2s resident in LDS, w1m restaged per cell (region overlaid by m^T),
//   w1s streamed from L2 (loop-invariant). M=16 rows/wave, 8 waves.
//   hebb_kernel unchanged (HBM roofline).

#define NCELL 256

typedef __attribute__((ext_vector_type(8))) short bf16x8;
typedef __attribute__((ext_vector_type(4))) float f32x4;
typedef __attribute__((ext_vector_type(4))) unsigned short u16x4;

#define MFMA(a, b, c) __builtin_amdgcn_mfma_f32_16x16x32_bf16((a), (b), (c), 0, 0, 0)

__device__ __forceinline__ unsigned short f2bf(float f) {
    return __builtin_bit_cast(unsigned short, __float2bfloat16(f));
}
__device__ __forceinline__ float frcp(float x) { return __builtin_amdgcn_rcpf(x); }
__device__ __forceinline__ float sigm(float v) { return frcp(1.0f + __expf(-v)); }
__device__ __forceinline__ float ftanh(float x) {
    float e = __expf(2.0f * x);
    return 1.0f - 2.0f * frcp(e + 1.0f);
}

// 16B-granule XOR swizzle within a row: col' = granule^(row&7) | sub-offset.
__device__ __forceinline__ int swzg(int col, int row) {
    return (((col >> 3) ^ (row & 7)) << 3) | (col & 7);
}
// per-wave [16][32] stage buffer swizzle
__device__ __forceinline__ int swb(int row, int col) {
    return row * 32 + ((((col >> 3) ^ row) & 3) << 3) + (col & 7);
}

// ws layout (ushort units): [0,8192) w1m img [128][64]; [8192,16384) w2m img
// [64][128]; [16384,49152) w1s LINEAR [256][128]; [49152,65536) w2s img [64][256].
__global__ void cvt_w(const float* __restrict__ a, const float* __restrict__ b,
                      const float* __restrict__ c, const float* __restrict__ d,
                      unsigned short* __restrict__ dst) {
    int i = blockIdx.x * 256 + threadIdx.x;   // 65536 total
    if (i < 8192) {                            // w1m [128][64] -> swizzled img
        int row = i >> 6, col = i & 63;
        dst[row * 64 + swzg(col, row)] = f2bf(a[i]);
    } else if (i < 16384) {                    // w2m [64][128] -> swizzled img
        int j = i - 8192;
        int row = j >> 7, col = j & 127;
        dst[8192 + row * 128 + swzg(col, row)] = f2bf(b[j]);
    } else if (i < 49152) {                    // w1s linear
        dst[i] = f2bf(c[i - 16384]);
    } else {                                   // w2s [64][256] -> swizzled img
        int j = i - 49152;
        int row = j >> 8, col = j & 255;
        dst[49152 + row * 256 + swzg(col, row)] = f2bf(d[j]);
    }
}

// ================= K1: persistent cell chain =================
__global__ __launch_bounds__(512, 4)
void cell_kernel(const float* __restrict__ x, const float* __restrict__ h,
                 const float* __restrict__ W, const float* __restrict__ decay,
                 const float* __restrict__ nid,
                 const float* __restrict__ sb1, const float* __restrict__ sb2,
                 const float* __restrict__ mb1, const float* __restrict__ mb2,
                 const float* __restrict__ injw, const float* __restrict__ injb,
                 const float* __restrict__ dgl,
                 const unsigned short* __restrict__ wbf,
                 float* __restrict__ out) {
    const int c    = blockIdx.x >> 1;
    const int half = blockIdx.x & 1;
    const int tid  = threadIdx.x;
    const int wv   = tid >> 6;                // 8 waves
    const int lane = tid & 63;
    const int lr = lane & 15;
    const int lg = lane >> 4;
    const int row0 = wv * 16;                 // wave owns rows row0..row0+15

    float* out_h = out;
    float* out_m = out + 16777216;
    float* out_d = out + 67108864;

    // LDS: 72.5 KB -> 2 blocks/CU
    __shared__ alignas(16) unsigned short dual_s[8192];   // 16K: w1m img / m^T
    __shared__ alignas(16) unsigned short w2m_s[8192];    // 16K persistent
    __shared__ alignas(16) unsigned short w2s_s[16384];   // 32K persistent
    __shared__ alignas(16) unsigned short hbuf_all[4096]; // 8K: per-wave [16][32]
    __shared__ float inj_s[128];                          // 512B (wave-0 private)
    unsigned short* hbuf = hbuf_all + wv * 512;

    // ---- stage persistent weight images (linear copy; swizzle pre-baked) ----
    {
        const uint4* s2m = (const uint4*)(wbf + 8192);
        const uint4* s2s = (const uint4*)(wbf + 49152);
        uint4* d2m = (uint4*)w2m_s;
        uint4* d2s = (uint4*)w2s_s;
        #pragma unroll
        for (int i = 0; i < 2; ++i) d2m[tid + i * 512] = s2m[tid + i * 512];
        #pragma unroll
        for (int i = 0; i < 4; ++i) d2s[tid + i * 512] = s2s[tid + i * 512];
    }

    // ---- per-c constants: nid A-frag values (f32, reused all 4 cells) ----
    float nv[2][8];
    {
        const float* nr = nid + (size_t)(c * 128 + row0 + lr) * 64;
        #pragma unroll
        for (int ks = 0; ks < 2; ++ks) {
            float4 n0 = *(const float4*)(nr + ks * 32 + lg * 8);
            float4 n1 = *(const float4*)(nr + ks * 32 + lg * 8 + 4);
            nv[ks][0] = n0.x; nv[ks][1] = n0.y; nv[ks][2] = n0.z; nv[ks][3] = n0.w;
            nv[ks][4] = n1.x; nv[ks][5] = n1.y; nv[ks][6] = n1.z; nv[ks][7] = n1.w;
        }
    }

    const unsigned short* w1s_g = wbf + 16384;   // linear [256][128] in L2

    for (int bb = 0; bb < 4; ++bb) {
        const int b = half * 4 + bb;
        const int cell = b * NCELL + c;

        __syncthreads();   // prev cell's m^T reads done / initial stage done

        // restage w1m image into dual_s (1024 x 16B, linear)
        {
            const uint4* s1m = (const uint4*)wbf;
            uint4* d1 = (uint4*)dual_s;
            #pragma unroll
            for (int i = 0; i < 2; ++i) d1[tid + i * 512] = s1m[tid + i * 512];
        }
        // wave-0: injection for this cell (inj_s wave-0 private)
        if (wv == 0) {
            const float* xr = x + cell * 64;
            const float* i0 = injw + (c * 128 + lane) * 64;
            const float* i1 = i0 + 64 * 64;
            float acc0 = injb[c * 128 + lane];
            float acc1 = injb[c * 128 + 64 + lane];
            #pragma unroll
            for (int d4 = 0; d4 < 16; ++d4) {
                float4 xv = ((const float4*)xr)[d4];
                float4 aa = ((const float4*)i0)[d4];
                float4 ab = ((const float4*)i1)[d4];
                acc0 += aa.x * xv.x + aa.y * xv.y + aa.z * xv.z + aa.w * xv.w;
                acc1 += ab.x * xv.x + ab.y * xv.y + ab.z * xv.z + ab.w * xv.w;
            }
            inj_s[lane] = acc0;
            inj_s[64 + lane] = acc1;
        }
        __syncthreads();   // w1m ready

        // ---- A-frags of h_id ----
        bf16x8 aH[2];
        {
            const float* hr = h + (size_t)(cell * 128 + row0 + lr) * 64;
            #pragma unroll
            for (int ks = 0; ks < 2; ++ks) {
                float4 a0 = *(const float4*)(hr + ks * 32 + lg * 8);
                float4 a1 = *(const float4*)(hr + ks * 32 + lg * 8 + 4);
                float v[8] = {a0.x, a0.y, a0.z, a0.w, a1.x, a1.y, a1.z, a1.w};
                unsigned short us[8];
                #pragma unroll
                for (int j = 0; j < 8; ++j) {
                    float hv = v[j] + nv[ks][j];
                    if (row0 + lr < 2) hv += inj_s[(row0 + lr) * 64 + ks * 32 + lg * 8 + j];
                    us[j] = f2bf(hv);
                }
                aH[ks] = *(bf16x8*)us;
            }
        }

        // ---- msg MLP (B from LDS) ----
        f32x4 accM[4];
        #pragma unroll
        for (int dt = 0; dt < 4; ++dt) accM[dt] = (f32x4){0.f, 0.f, 0.f, 0.f};
        #pragma unroll
        for (int ch = 0; ch < 4; ++ch) {
            f32x4 accH[2];
            accH[0] = (f32x4){0.f, 0.f, 0.f, 0.f};
            accH[1] = (f32x4){0.f, 0.f, 0.f, 0.f};
            #pragma unroll
            for (int ks = 0; ks < 2; ++ks)
                #pragma unroll
                for (int ht = 0; ht < 2; ++ht) {
                    const int wrow = ch * 32 + ht * 16 + lr;
                    bf16x8 bw = *(const bf16x8*)&dual_s[wrow * 64 + swzg(ks * 32 + lg * 8, wrow)];
                    accH[ht] = MFMA(aH[ks], bw, accH[ht]);
                }
            #pragma unroll
            for (int ht = 0; ht < 2; ++ht) {
                float b1v = mb1[ch * 32 + ht * 16 + lr];
                #pragma unroll
                for (int r = 0; r < 4; ++r)
                    hbuf[swb(lg * 4 + r, ht * 16 + lr)] = f2bf(ftanh(accH[ht][r] + b1v));
            }
            bf16x8 aM = *(const bf16x8*)&hbuf[swb(lr, lg * 8)];
            #pragma unroll
            for (int dt = 0; dt < 4; ++dt) {
                const int wrow = dt * 16 + lr;
                bf16x8 bw = *(const bf16x8*)&w2m_s[wrow * 128 + swzg(ch * 32 + lg * 8, wrow)];
                accM[dt] = MFMA(aM, bw, accM[dt]);
            }
        }
        // m epilogue: f32 to global; bf16 kept for m^T
        unsigned short us_m[4][4];
        #pragma unroll
        for (int dt = 0; dt < 4; ++dt) {
            float b2v = mb2[dt * 16 + lr];
            #pragma unroll
            for (int r = 0; r < 4; ++r) {
                float mv = accM[dt][r] + b2v;
                out_m[(size_t)(cell * 128 + row0 + lg * 4 + r) * 64 + dt * 16 + lr] = mv;
                us_m[dt][r] = f2bf(mv);
            }
        }
        __syncthreads();   // all w1m reads done -> safe to overwrite dual_s

        // write m^T [64][128] into dual_s
        #pragma unroll
        for (int dt = 0; dt < 4; ++dt)
            #pragma unroll
            for (int r = 0; r < 4; ++r) {
                const int d = dt * 16 + lr;
                dual_s[d * 128 + swzg(row0 + lg * 4 + r, d)] = us_m[dt][r];
            }
        __syncthreads();   // m^T ready

        // ---- agg = W @ m ----
        f32x4 accA[4];
        #pragma unroll
        for (int dt = 0; dt < 4; ++dt) accA[dt] = (f32x4){0.f, 0.f, 0.f, 0.f};
        {
            const float* Wr = W + (size_t)cell * 16384 + (row0 + lr) * 128;
            #pragma unroll
            for (int ks = 0; ks < 4; ++ks) {
                float4 wa = *(const float4*)(Wr + ks * 32 + lg * 8);
                float4 wb = *(const float4*)(Wr + ks * 32 + lg * 8 + 4);
                unsigned short uw[8] = {f2bf(wa.x), f2bf(wa.y), f2bf(wa.z), f2bf(wa.w),
                                        f2bf(wb.x), f2bf(wb.y), f2bf(wb.z), f2bf(wb.w)};
                bf16x8 aW = *(bf16x8*)uw;
                #pragma unroll
                for (int dt = 0; dt < 4; ++dt) {
                    const int mrow = dt * 16 + lr;
                    bf16x8 bm = *(const bf16x8*)&dual_s[mrow * 128 + swzg(ks * 32 + lg * 8, mrow)];
                    accA[dt] = MFMA(aW, bm, accA[dt]);
                }
            }
        }
        // C->A relayout via own-wave hbuf, 2 passes of 32 cols
        bf16x8 aG[2];
        #pragma unroll
        for (int p = 0; p < 2; ++p) {
            #pragma unroll
            for (int q = 0; q < 2; ++q)
                #pragma unroll
                for (int r = 0; r < 4; ++r)
                    hbuf[swb(lg * 4 + r, q * 16 + lr)] = f2bf(accA[p * 2 + q][r]);
            aG[p] = *(const bf16x8*)&hbuf[swb(lr, lg * 8)];
        }

        // ---- state MLP (w1s from L2, w2s from LDS) ----
        f32x4 accD[4];
        #pragma unroll
        for (int dt = 0; dt < 4; ++dt) accD[dt] = (f32x4){0.f, 0.f, 0.f, 0.f};
        #pragma unroll 2
        for (int ch = 0; ch < 8; ++ch) {
            f32x4 accS[2];
            accS[0] = (f32x4){0.f, 0.f, 0.f, 0.f};
            accS[1] = (f32x4){0.f, 0.f, 0.f, 0.f};
            #pragma unroll
            for (int ks = 0; ks < 4; ++ks) {
                bf16x8 af = (ks < 2) ? aH[ks] : aG[ks - 2];
                #pragma unroll
                for (int ht = 0; ht < 2; ++ht) {
                    bf16x8 bw = *(const bf16x8*)&w1s_g[(ch * 32 + ht * 16 + lr) * 128 + ks * 32 + lg * 8];
                    accS[ht] = MFMA(af, bw, accS[ht]);
                }
            }
            #pragma unroll
            for (int ht = 0; ht < 2; ++ht) {
                float bv = sb1[ch * 32 + ht * 16 + lr];
                #pragma unroll
                for (int r = 0; r < 4; ++r)
                    hbuf[swb(lg * 4 + r, ht * 16 + lr)] = f2bf(ftanh(accS[ht][r] + bv));
            }
            bf16x8 aS = *(const bf16x8*)&hbuf[swb(lr, lg * 8)];
            #pragma unroll
            for (int dt = 0; dt < 4; ++dt) {
                const int wrow = dt * 16 + lr;
                bf16x8 bw = *(const bf16x8*)&w2s_s[wrow * 256 + swzg(ch * 32 + lg * 8, wrow)];
                accD[dt] = MFMA(aS, bw, accD[dt]);
            }
        }

        // ---- decay_new, h_new ----
        float dnew[4];
        #pragma unroll
        for (int r = 0; r < 4; ++r) {
            float s = 0.f;
            #pragma unroll
            for (int dt = 0; dt < 4; ++dt) {
                accD[dt][r] += sb2[dt * 16 + lr];
                s += accD[dt][r];
            }
            s += __shfl_xor(s, 1);
            s += __shfl_xor(s, 2);
            s += __shfl_xor(s, 4);
            s += __shfl_xor(s, 8);
            int row = row0 + lg * 4 + r;
            float mean = s * (1.0f / 64.0f);
            float dg = 0.5f * sigm(dgl[c * 128 + row]);
            float dn = (1.0f - dg) * decay[cell * 128 + row] + dg * sigm(mean);
            if (lr == 0) out_d[cell * 128 + row] = dn;
            dnew[r] = dn;
        }
        #pragma unroll
        for (int r = 0; r < 4; ++r) {
            int row = row0 + lg * 4 + r;
            float dn = dnew[r];
            const float* hrr = h + (size_t)(cell * 128 + row) * 64;
            #pragma unroll
            for (int dt = 0; dt < 4; ++dt) {
                int col = dt * 16 + lr;
                float hpost = hrr[col];
                if (row < 2) hpost += inj_s[row * 64 + col];
                float hn = (1.0f - dn) * hpost + dn * ftanh(accD[dt][r]);
                out_h[(size_t)(cell * 128 + row) * 64 + col] = hn;
            }
        }
    }
}

// ================= K2: outer + hebbian/W streaming update =================
__device__ __forceinline__ int sw64(int row, int col) {
    return row * 64 + ((((col >> 3) ^ row) & 7) << 3) + (col & 7);
}

__global__ __launch_bounds__(256, 4)
void hebb_kernel(const float* __restrict__ W, const float* __restrict__ hebb,
                 const float* __restrict__ wdl, const float* __restrict__ hdl,
                 float* __restrict__ out) {
    const int cell = blockIdx.x;
    const int c = cell & (NCELL - 1);
    const int tid = threadIdx.x;
    const int wv = tid >> 6;
    const int lane = tid & 63;
    const int lr = lane & 15;
    const int lg = lane >> 4;

    const float* hsrc = out + (size_t)cell * 8192;              // h_new
    const float* msrc = out + 16777216 + (size_t)cell * 8192;   // m
    float* out_W  = out + 33554432;
    float* out_hb = out + 67371008;

    __shared__ alignas(16) unsigned char smem[32768];
    unsigned short* hA = (unsigned short*)smem;            // [128][64] h_new bf16
    unsigned short* mB = (unsigned short*)(smem + 16384);  // [128][64] m bf16

    #pragma unroll
    for (int g = 0; g < 8; ++g) {
        int idx = g * 1024 + tid * 4;
        int row = idx >> 6, col = idx & 63;
        float4 hv = *(const float4*)(hsrc + idx);
        float4 mv = *(const float4*)(msrc + idx);
        u16x4 hu = {f2bf(hv.x), f2bf(hv.y), f2bf(hv.z), f2bf(hv.w)};
        u16x4 mu = {f2bf(mv.x), f2bf(mv.y), f2bf(mv.z), f2bf(mv.w)};
        *(u16x4*)&hA[sw64(row, col)] = hu;
        *(u16x4*)&mB[sw64(row, col)] = mu;
    }
    __syncthreads();

    bf16x8 aO[2][2];
    #pragma unroll
    for (int rt = 0; rt < 2; ++rt)
        #pragma unroll
        for (int ks = 0; ks < 2; ++ks)
            aO[rt][ks] = *(const bf16x8*)&hA[sw64(wv * 32 + rt * 16 + lr, ks * 32 + lg * 8)];

    f32x4 accO[2][8];
    #pragma unroll
    for (int rt = 0; rt < 2; ++rt)
        #pragma unroll
        for (int jt = 0; jt < 8; ++jt)
            accO[rt][jt] = (f32x4){0.f, 0.f, 0.f, 0.f};
    #pragma unroll
    for (int jt = 0; jt < 8; ++jt)
        #pragma unroll
        for (int ks = 0; ks < 2; ++ks) {
            bf16x8 bm = *(const bf16x8*)&mB[sw64(jt * 16 + lr, ks * 32 + lg * 8)];
            #pragma unroll
            for (int rt = 0; rt < 2; ++rt)
                accO[rt][jt] = MFMA(aO[rt][ks], bm, accO[rt][jt]);
        }

    #pragma unroll
    for (int rt = 0; rt < 2; ++rt)
        #pragma unroll
        for (int r = 0; r < 4; ++r) {
            int i = wv * 32 + rt * 16 + lg * 4 + r;
            float hg = 0.5f * sigm(hdl[c * 128 + i]);
            float wg = 0.5f * sigm(wdl[c * 128 + i]);
            const float* hbr = hebb + (size_t)(cell * 128 + i) * 128;
            const float* Wr = W + (size_t)(cell * 128 + i) * 128;
            float* ohb = out_hb + (size_t)(cell * 128 + i) * 128;
            float wpre[8];
            float ss = 0.f;
            #pragma unroll
            for (int jt = 0; jt < 8; ++jt) {
                int j = jt * 16 + lr;
                float o = accO[rt][jt][r] * (1.0f / 64.0f);
                float hbn = (1.0f - hg) * hbr[j] + hg * o;
                ohb[j] = hbn;
                float wp = (1.0f - wg) * Wr[j] + wg * hbn;
                wpre[jt] = wp;
                ss += wp * wp;
            }
            ss += __shfl_xor(ss, 1);
            ss += __shfl_xor(ss, 2);
            ss += __shfl_xor(ss, 4);
            ss += __shfl_xor(ss, 8);
            float scale = rsqrtf(ss * (1.0f / 128.0f) + 1e-6f);
            float* oW = out_W + (size_t)(cell * 128 + i) * 128;
            #pragma unroll
            for (int jt = 0; jt < 8; ++jt)
                oW[jt * 16 + lr] = wpre[jt] * scale;
        }
}

extern "C" void kernel_launch(void* const* d_in, const int* in_sizes, int n_in,
                              void* d_out, int out_size, void* d_ws, size_t ws_size,
                              hipStream_t stream) {
    const float* x    = (const float*)d_in[0];
    const float* h    = (const float*)d_in[1];
    const float* W    = (const float*)d_in[2];
    const float* dec  = (const float*)d_in[3];
    const float* hebb = (const float*)d_in[4];
    const float* nid  = (const float*)d_in[5];
    const float* sw1  = (const float*)d_in[6];
    const float* sb1  = (const float*)d_in[7];
    const float* sw2  = (const float*)d_in[8];
    const float* sb2  = (const float*)d_in[9];
    const float* mw1  = (const float*)d_in[10];
    const float* mb1  = (const float*)d_in[11];
    const float* mw2  = (const float*)d_in[12];
    const float* mb2  = (const float*)d_in[13];
    const float* injw = (const float*)d_in[14];
    const float* injb = (const float*)d_in[15];
    const float* wdl  = (const float*)d_in[16];
    const float* dgl  = (const float*)d_in[17];
    const float* hdl  = (const float*)d_in[18];

    unsigned short* wbf = (unsigned short*)d_ws;   // 65536 bf16 = 128 KB

    cvt_w<<<256, 256, 0, stream>>>(mw1, mw2, sw1, sw2, wbf);
    cell_kernel<<<512, 512, 0, stream>>>(x, h, W, dec, nid, sb1, sb2, mb1, mb2,
                                         injw, injb, dgl, wbf, (float*)d_out);
    hebb_kernel<<<2048, 256, 0, stream>>>(W, hebb, wdl, hdl, (float*)d_out);
}